// Round 5
// baseline (553.841 us; speedup 1.0000x reference)
//
#include <hip/hip_runtime.h>
#include <stdint.h>

typedef unsigned long long u64;
typedef unsigned int u32;

#define NIMG 16
#define NC 80
#define HW 25600
#define CHW (NC * HW)          // 2,048,000
#define PREK 1000
#define POSTK 200
#define HB2 2048               // coarse bins: float bits >> 19
#define CAPLDS 4096            // LDS sort capacity (selected ~1075 expected)
#define CANDCAP 131072
#define STAGE_CAP 2048
#define EPB 16384              // elements per k_scan block
#define GROWS 500              // sup rows per k_greedy LDS phase (64,000 B)
#define LOGIT_T (-2.9444389791664403f)   // ln(0.05/0.95)
#define SFLOOR 0.05f
#define CLIPDWH 4.135166556742356f        // ln(1000/16)
#define IMGM1 1279.0f
#define OFFMUL 1281.0f
#define NMSTHR 0.8f

// ---- K1: stream 131 MB, compact candidates (s > 0.05) ----------------------
__global__ __launch_bounds__(256) void k_scan(const float* __restrict__ cls,
                                              const float* __restrict__ ctr,
                                              int* __restrict__ gcount,
                                              u64* __restrict__ cand) {
  __shared__ u64 stg[STAGE_CAP];                 // 16 KB
  __shared__ int scnt, sbase;
  const int n = blockIdx.y, tid = threadIdx.x, lane = tid & 63;
  if (tid == 0) scnt = 0;
  __syncthreads();
  const float* ctrRow = ctr + (size_t)n * HW;
  const size_t base = (size_t)n * CHW + (size_t)blockIdx.x * EPB;
  for (int it = 0; it < 16; ++it) {
    const int e0 = it * 1024 + tid * 4;
    const float4 v = *reinterpret_cast<const float4*>(cls + base + e0);
    const float L[4] = {v.x, v.y, v.z, v.w};
#pragma unroll
    for (int u = 0; u < 4; ++u) {
      const int e = blockIdx.x * EPB + e0 + u;   // within-image element id
      bool pass = false;
      u64 pk = 0;
      if (L[u] > LOGIT_T) {                      // prob > 0.05 pre-filter
        float p  = 1.0f / (1.0f + expf(-L[u]));
        int loc = e % HW;
        float cg = 1.0f / (1.0f + expf(-ctrRow[loc]));
        float s = p * cg;
        if (s > SFLOOR) {
          int c = e / HW;
          u32 idx = (u32)(loc * NC + c);         // reference flat index [HW, C]
          pk = ((u64)__float_as_uint(s) << 32) | (u32)(~idx);
          pass = true;
        }
      }
      u64 m = __ballot(pass);
      if (m) {                                   // wave-aggregated stage push
        int leader = __ffsll(m) - 1;
        int basew = 0;
        if (lane == leader) basew = atomicAdd(&scnt, __popcll(m));
        basew = __shfl(basew, leader);
        if (pass) {
          int pos = basew + __popcll(m & ((1ULL << lane) - 1ULL));
          if (pos < STAGE_CAP) stg[pos] = pk;
          else {                                 // never expected (690 << 2048)
            int gp = atomicAdd(&gcount[n], 1);
            if (gp < CANDCAP) cand[(size_t)n * CANDCAP + gp] = pk;
          }
        }
      }
    }
  }
  __syncthreads();
  if (tid == 0) {                                // one global atomic per block
    int c = scnt < STAGE_CAP ? scnt : STAGE_CAP;
    sbase = atomicAdd(&gcount[n], c);
  }
  __syncthreads();
  int c = scnt < STAGE_CAP ? scnt : STAGE_CAP;
  for (int i = tid; i < c; i += 256) {
    int gp = sbase + i;
    if (gp < CANDCAP) cand[(size_t)n * CANDCAP + gp] = stg[i];
  }
}

// ---- K2: per-image fused hist -> cutoff -> select -> bitonic sort ----------
__global__ __launch_bounds__(1024) void k_selsort(const u64* __restrict__ cand,
                                                  const int* __restrict__ gcount,
                                                  u64* __restrict__ top,
                                                  int* __restrict__ gnc) {
  __shared__ u64 a[CAPLDS];                      // 32 KB sort arena
  __shared__ int hh[HB2];                        // 8 KB histogram
  __shared__ int ss[1024];                       // 4 KB suffix-scan
  __shared__ int sB, selK;
  const int n = blockIdx.x, t = threadIdx.x, lane = t & 63;
  int cnt = gcount[n]; if (cnt > CANDCAP) cnt = CANDCAP;
  for (int i = t; i < HB2; i += 1024) hh[i] = 0;
  for (int i = t; i < CAPLDS; i += 1024) a[i] = 0ULL;
  if (t == 0) { selK = 0; sB = HB2; }
  __syncthreads();
  const u64* C = cand + (size_t)n * CANDCAP;
  // pass A: LDS histogram of score keys
  for (int i = t; i < cnt; i += 1024)
    atomicAdd(&hh[(u32)(C[i] >> 51)], 1);        // key = score bits >> 19
  __syncthreads();
  ss[t] = hh[2 * t] + hh[2 * t + 1];
  __syncthreads();
  for (int off = 1; off < 1024; off <<= 1) {     // inclusive suffix scan
    int v = (t + off < 1024) ? ss[t + off] : 0;
    __syncthreads();
    ss[t] += v;
    __syncthreads();
  }
  const int total = ss[0];
  const int ncand = total < PREK ? total : PREK;
  if (t == 0) gnc[n] = ncand;
  if (total > 0) {
    int Sn = (t < 1023) ? ss[t + 1] : 0;
    if (ss[t] >= ncand && Sn < ncand) {          // unique boundary chunk of 2
      int run = Sn, B = 2 * t;
      for (int b = 2 * t + 1; b >= 2 * t; --b) {
        run += hh[b];
        if (run >= ncand) { B = b; break; }
      }
      sB = B;
    }
  }
  __syncthreads();
  const u32 B = (u32)sB;
  // pass B: select bin >= B into LDS arena (wave-aggregated LDS counter)
  const int cntR = (cnt + 1023) & ~1023;         // uniform trip count for ballot
  for (int i = t; i < cntR; i += 1024) {
    bool pass = false; u64 pk = 0;
    if (i < cnt) { pk = C[i]; pass = ((u32)(pk >> 51) >= B); }
    u64 m = __ballot(pass);
    if (m) {
      int leader = __ffsll(m) - 1;
      int basew = 0;
      if (lane == leader) basew = atomicAdd(&selK, __popcll(m));
      basew = __shfl(basew, leader);
      if (pass) {
        int pos = basew + __popcll(m & ((1ULL << lane) - 1ULL));
        if (pos < CAPLDS) a[pos] = pk;           // overflow impossible in practice
      }
    }
  }
  __syncthreads();
  // bitonic sort descending (u64 keys; 0 sorts last)
  for (int k = 2; k <= CAPLDS; k <<= 1)
    for (int j = k >> 1; j > 0; j >>= 1) {
      for (int i = t; i < CAPLDS; i += 1024) {
        int ix = i ^ j;
        if (ix > i) {
          u64 x = a[i], y = a[ix];
          bool desc = ((i & k) == 0);
          if (desc ? (x < y) : (x > y)) { a[i] = y; a[ix] = x; }
        }
      }
      __syncthreads();
    }
  if (t < 1024) top[(size_t)n * 1024 + t] = a[t];
}

// ---- K3: decode boxes, det-scores, offset boxes ----------------------------
__global__ void k_decode(const u64* __restrict__ top, const int* __restrict__ gnc,
                         const float* __restrict__ reg, const float* __restrict__ anch,
                         float4* __restrict__ boxes, float4* __restrict__ nb,
                         float* __restrict__ dsc) {
  const int n = blockIdx.x, k = threadIdx.x;
  if (k >= PREK) return;
  u64 pk = top[(size_t)n * 1024 + k];
  int ncand = gnc[n];
  float4 bx = {0, 0, 0, 0}, nbv = {0, 0, 0, 0};
  float d = 0.0f;
  if (k < ncand && pk != 0ULL) {
    float s = __uint_as_float((u32)(pk >> 32));
    u32 idx = ~(u32)pk;
    int loc = idx / NC, c = idx - loc * NC;
    float r0 = reg[((size_t)n * 4 + 0) * HW + loc];
    float r1 = reg[((size_t)n * 4 + 1) * HW + loc];
    float r2 = reg[((size_t)n * 4 + 2) * HW + loc];
    float r3 = reg[((size_t)n * 4 + 3) * HW + loc];
    float a0 = anch[loc * 4 + 0], a1 = anch[loc * 4 + 1];
    float a2 = anch[loc * 4 + 2], a3 = anch[loc * 4 + 3];
    float w = a2 - a0 + 1.0f, h = a3 - a1 + 1.0f;
    float cx = a0 + 0.5f * w, cy = a1 + 0.5f * h;
    float dx = r0 / 10.0f, dy = r1 / 10.0f;
    float dw = fminf(r2 / 5.0f, CLIPDWH), dh = fminf(r3 / 5.0f, CLIPDWH);
    float pcx = dx * w + cx, pcy = dy * h + cy;
    float pw = expf(dw) * w, ph = expf(dh) * h;
    float x1 = pcx - 0.5f * pw, y1 = pcy - 0.5f * ph;
    float x2 = pcx + 0.5f * pw - 1.0f, y2 = pcy + 0.5f * ph - 1.0f;
    x1 = fminf(fmaxf(x1, 0.0f), IMGM1); y1 = fminf(fmaxf(y1, 0.0f), IMGM1);
    x2 = fminf(fmaxf(x2, 0.0f), IMGM1); y2 = fminf(fmaxf(y2, 0.0f), IMGM1);
    float wsz = x2 - x1 + 1.0f, hsz = y2 - y1 + 1.0f;
    if (wsz >= 0.0f && hsz >= 0.0f) d = sqrtf(s);
    bx = {x1, y1, x2, y2};
    float off = (float)(c + 1) * OFFMUL;        // reference adds offset AFTER clip
    nbv = {x1 + off, y1 + off, x2 + off, y2 + off};
  }
  boxes[n * PREK + k] = bx;
  nb[n * PREK + k] = nbv;
  dsc[n * PREK + k] = d;
}

// ---- K4: suppression bitmask matrix ----------------------------------------
__global__ void k_sup(const float4* __restrict__ nb, const float* __restrict__ dsc,
                      u64* __restrict__ sup) {
  const int i = blockIdx.x, n = blockIdx.y;
  if (dsc[n * PREK + i] == 0.0f) return;        // row never read in greedy phase
  const float4 bi = nb[n * PREK + i];
  const float a1 = fmaxf(bi.z - bi.x, 0.0f) * fmaxf(bi.w - bi.y, 0.0f);
  const int tid = threadIdx.x, lane = tid & 63, wv = tid >> 6;
#pragma unroll
  for (int rep = 0; rep < 4; ++rep) {
    int j = rep * 256 + tid;
    bool bit = false;
    if (j < PREK && j > i) {
      float4 bj = nb[n * PREK + j];
      float xx1 = fmaxf(bi.x, bj.x), yy1 = fmaxf(bi.y, bj.y);
      float xx2 = fminf(bi.z, bj.z), yy2 = fminf(bi.w, bj.w);
      float inter = fmaxf(xx2 - xx1, 0.0f) * fmaxf(yy2 - yy1, 0.0f);
      float a2 = fmaxf(bj.z - bj.x, 0.0f) * fmaxf(bj.w - bj.y, 0.0f);
      float iou = inter / fmaxf(a1 + a2 - inter, 1e-9f);
      bit = iou > NMSTHR;
    }
    u64 m = __ballot(bit);
    if (lane == 0) sup[((size_t)n * PREK + i) * 16 + rep * 4 + wv] = m;
  }
}

// ---- K5: greedy NMS with LDS-resident sup (2 phases of 500 rows) -----------
__global__ __launch_bounds__(1024) void k_greedy(const float* __restrict__ dsc,
                                                 const float4* __restrict__ boxes,
                                                 const u64* __restrict__ sup,
                                                 float* __restrict__ out) {
  __shared__ u64 S[GROWS * 16];                  // 64,000 B
  const int n = blockIdx.x, t = threadIdx.x, lane = t & 63;
  const u64* Sg = sup + (size_t)n * PREK * 16;
  const float* d = dsc + n * PREK;
  u64 keep0 = 0, removed = 0;
  if (t < 64) {                                  // wave 0: build keep0
    for (int w = 0; w < 16; ++w) {
      int i = w * 64 + lane;
      bool b = (i < PREK) && (d[i] > 0.0f);
      u64 m = __ballot(b);
      if (lane == w) keep0 = m;
    }
  }
  for (int ph = 0; ph < 2; ++ph) {
    const int rbase = ph * GROWS;
    __syncthreads();
    // cooperative load of 500 rows (64 KB) into LDS, float4-wide
    const float4* src = (const float4*)(Sg + (size_t)rbase * 16);
    float4* dst = (float4*)S;
    for (int i = t; i < GROWS * 8; i += 1024) dst[i] = src[i];
    __syncthreads();
    if (t < 64) {                                // wave 0: serial greedy chain
#define LDSR(lr) ((lane < 16 && (u32)(lr) < (u32)GROWS) ? S[(lr) * 16 + lane] : 0ULL)
      u64 p0 = LDSR(0), p1 = LDSR(1), p2 = LDSR(2), p3 = LDSR(3);
      u64 p4 = LDSR(4), p5 = LDSR(5), p6 = LDSR(6), p7 = LDSR(7);
#define STEP(ii, pr) { \
      u64 cur = __shfl(keep0 & ~removed, (ii) >> 6); \
      if ((cur >> ((ii) & 63)) & 1ULL) removed |= pr; \
      pr = LDSR((ii) - rbase + 8); }
      for (int ib = rbase; ib < rbase + GROWS; ib += 4) {
        STEP(ib + 0, p0) STEP(ib + 1, p1) STEP(ib + 2, p2) STEP(ib + 3, p3)
        ib += 4;
        STEP(ib + 0, p4) STEP(ib + 1, p5) STEP(ib + 2, p6) STEP(ib + 3, p7)
        ib -= 4;
      }
#undef STEP
#undef LDSR
    }
  }
  __syncthreads();
  if (t < 64) {                                  // wave 0: ranked output
    u64 fk = keep0 & ~removed;
    int base = 0;
    for (int w = 0; w < 16; ++w) {
      u64 m = __shfl(fk, w);
      int i = w * 64 + lane;
      bool kept = (m >> lane) & 1ULL;
      int rank = base + __popcll(m & ((1ULL << lane) - 1ULL));
      if (kept && rank < POSTK && i < PREK) {
        float4 b = boxes[n * PREK + i];
        float* o = out + ((size_t)n * POSTK + rank) * 5;
        o[0] = b.x; o[1] = b.y; o[2] = b.z; o[3] = b.w; o[4] = d[i];
      }
      base += __popcll(m);
    }
  }
}

// ---- launch -----------------------------------------------------------------
extern "C" void kernel_launch(void* const* d_in, const int* in_sizes, int n_in,
                              void* d_out, int out_size, void* d_ws, size_t ws_size,
                              hipStream_t stream) {
  (void)in_sizes; (void)n_in; (void)ws_size;
  const float* cls  = (const float*)d_in[0];
  const float* reg  = (const float*)d_in[1];
  const float* ctr  = (const float*)d_in[2];
  const float* anch = (const float*)d_in[3];
  float* out = (float*)d_out;
  char* ws = (char*)d_ws;

  int*    gcount = (int*)(ws + 0);             // 64
  int*    gnc    = (int*)(ws + 64);            // 64
  u64*    cand   = (u64*)(ws + 128);           // 16*131072*8 = 16,777,216
  u64*    top    = (u64*)(ws + 16777344);      // 16*1024*8 = 131,072
  float4* boxes  = (float4*)(ws + 16908416);   // 16*1000*16 = 256,000
  float4* nb     = (float4*)(ws + 17164416);   // 256,000
  float*  dsc    = (float*)(ws + 17420416);    // 64,000
  u64*    sup    = (u64*)(ws + 17484416);      // 16*1000*16*8 = 2,048,000 -> end 19,532,416

  hipMemsetAsync(ws, 0, 128, stream);                          // gcount (+gnc)
  hipMemsetAsync(d_out, 0, (size_t)out_size * sizeof(float), stream);

  dim3 gScan(CHW / EPB, NIMG);                 // 125 x 16 blocks
  k_scan   <<<gScan, 256, 0, stream>>>(cls, ctr, gcount, cand);
  k_selsort<<<NIMG, 1024, 0, stream>>>(cand, gcount, top, gnc);
  k_decode <<<NIMG, 1024, 0, stream>>>(top, gnc, reg, anch, boxes, nb, dsc);
  dim3 gSup(PREK, NIMG);
  k_sup    <<<gSup, 256, 0, stream>>>(nb, dsc, sup);
  k_greedy <<<NIMG, 1024, 0, stream>>>(dsc, boxes, sup, out);
}

// Round 6
// 502.142 us; speedup vs baseline: 1.1030x; 1.1030x over previous
//
#include <hip/hip_runtime.h>
#include <stdint.h>

typedef unsigned long long u64;
typedef unsigned int u32;

#define NIMG 16
#define NC 80
#define HW 25600
#define CHW (NC * HW)          // 2,048,000
#define PREK 1000
#define POSTK 200
#define HB2 2048               // coarse bins: float bits >> 19
#define CAPLDS 4096            // LDS sort capacity (selected ~1075 expected)
#define CANDCAP 131072
#define STAGE_CAP 2048
#define EPB 16384              // elements per k_scan block
#define CCAP 128               // per-class box capacity (mean 12.5, 128 = 30+ sigma)
#define LOGIT_T (-2.9444389791664403f)   // ln(0.05/0.95)
#define SFLOOR 0.05f
#define CLIPDWH 4.135166556742356f        // ln(1000/16)
#define IMGM1 1279.0f
#define OFFMUL 1281.0f
#define NMSTHR 0.8f

// ---- K1: stream 131 MB, compact candidates (s > 0.05) ----------------------
__global__ __launch_bounds__(256) void k_scan(const float* __restrict__ cls,
                                              const float* __restrict__ ctr,
                                              int* __restrict__ gcount,
                                              u64* __restrict__ cand) {
  __shared__ u64 stg[STAGE_CAP];                 // 16 KB
  __shared__ int scnt, sbase;
  const int n = blockIdx.y, tid = threadIdx.x, lane = tid & 63;
  if (tid == 0) scnt = 0;
  __syncthreads();
  const float* ctrRow = ctr + (size_t)n * HW;
  const size_t base = (size_t)n * CHW + (size_t)blockIdx.x * EPB;
  for (int it = 0; it < 16; ++it) {
    const int e0 = it * 1024 + tid * 4;
    const float4 v = *reinterpret_cast<const float4*>(cls + base + e0);
    const float L[4] = {v.x, v.y, v.z, v.w};
#pragma unroll
    for (int u = 0; u < 4; ++u) {
      const int e = blockIdx.x * EPB + e0 + u;   // within-image element id
      bool pass = false;
      u64 pk = 0;
      if (L[u] > LOGIT_T) {                      // prob > 0.05 pre-filter
        float p  = 1.0f / (1.0f + expf(-L[u]));
        int loc = e % HW;
        float cg = 1.0f / (1.0f + expf(-ctrRow[loc]));
        float s = p * cg;
        if (s > SFLOOR) {
          int c = e / HW;
          u32 idx = (u32)(loc * NC + c);         // reference flat index [HW, C]
          pk = ((u64)__float_as_uint(s) << 32) | (u32)(~idx);
          pass = true;
        }
      }
      u64 m = __ballot(pass);
      if (m) {                                   // wave-aggregated stage push
        int leader = __ffsll(m) - 1;
        int basew = 0;
        if (lane == leader) basew = atomicAdd(&scnt, __popcll(m));
        basew = __shfl(basew, leader);
        if (pass) {
          int pos = basew + __popcll(m & ((1ULL << lane) - 1ULL));
          if (pos < STAGE_CAP) stg[pos] = pk;
          else {                                 // never expected (690 << 2048)
            int gp = atomicAdd(&gcount[n], 1);
            if (gp < CANDCAP) cand[(size_t)n * CANDCAP + gp] = pk;
          }
        }
      }
    }
  }
  __syncthreads();
  if (tid == 0) {                                // one global atomic per block
    int c = scnt < STAGE_CAP ? scnt : STAGE_CAP;
    sbase = atomicAdd(&gcount[n], c);
  }
  __syncthreads();
  int c = scnt < STAGE_CAP ? scnt : STAGE_CAP;
  for (int i = tid; i < c; i += 256) {
    int gp = sbase + i;
    if (gp < CANDCAP) cand[(size_t)n * CANDCAP + gp] = stg[i];
  }
}

// ---- K2: per-image fused hist -> cutoff -> select -> bitonic sort ----------
__global__ __launch_bounds__(1024) void k_selsort(const u64* __restrict__ cand,
                                                  const int* __restrict__ gcount,
                                                  u64* __restrict__ top,
                                                  int* __restrict__ gnc) {
  __shared__ u64 a[CAPLDS];                      // 32 KB sort arena
  __shared__ int hh[HB2];                        // 8 KB histogram
  __shared__ int ss[1024];                       // 4 KB suffix-scan
  __shared__ int sB, selK;
  const int n = blockIdx.x, t = threadIdx.x, lane = t & 63;
  int cnt = gcount[n]; if (cnt > CANDCAP) cnt = CANDCAP;
  for (int i = t; i < HB2; i += 1024) hh[i] = 0;
  for (int i = t; i < CAPLDS; i += 1024) a[i] = 0ULL;
  if (t == 0) { selK = 0; sB = HB2; }
  __syncthreads();
  const u64* C = cand + (size_t)n * CANDCAP;
  // pass A: LDS histogram of score keys
  for (int i = t; i < cnt; i += 1024)
    atomicAdd(&hh[(u32)(C[i] >> 51)], 1);        // key = score bits >> 19
  __syncthreads();
  ss[t] = hh[2 * t] + hh[2 * t + 1];
  __syncthreads();
  for (int off = 1; off < 1024; off <<= 1) {     // inclusive suffix scan
    int v = (t + off < 1024) ? ss[t + off] : 0;
    __syncthreads();
    ss[t] += v;
    __syncthreads();
  }
  const int total = ss[0];
  const int ncand = total < PREK ? total : PREK;
  if (t == 0) gnc[n] = ncand;
  if (total > 0) {
    int Sn = (t < 1023) ? ss[t + 1] : 0;
    if (ss[t] >= ncand && Sn < ncand) {          // unique boundary chunk of 2
      int run = Sn, B = 2 * t;
      for (int b = 2 * t + 1; b >= 2 * t; --b) {
        run += hh[b];
        if (run >= ncand) { B = b; break; }
      }
      sB = B;
    }
  }
  __syncthreads();
  const u32 B = (u32)sB;
  // pass B: select bin >= B into LDS arena (wave-aggregated LDS counter)
  const int cntR = (cnt + 1023) & ~1023;         // uniform trip count for ballot
  for (int i = t; i < cntR; i += 1024) {
    bool pass = false; u64 pk = 0;
    if (i < cnt) { pk = C[i]; pass = ((u32)(pk >> 51) >= B); }
    u64 m = __ballot(pass);
    if (m) {
      int leader = __ffsll(m) - 1;
      int basew = 0;
      if (lane == leader) basew = atomicAdd(&selK, __popcll(m));
      basew = __shfl(basew, leader);
      if (pass) {
        int pos = basew + __popcll(m & ((1ULL << lane) - 1ULL));
        if (pos < CAPLDS) a[pos] = pk;           // overflow impossible in practice
      }
    }
  }
  __syncthreads();
  // bitonic sort descending (u64 keys; 0 sorts last)
  for (int k = 2; k <= CAPLDS; k <<= 1)
    for (int j = k >> 1; j > 0; j >>= 1) {
      for (int i = t; i < CAPLDS; i += 1024) {
        int ix = i ^ j;
        if (ix > i) {
          u64 x = a[i], y = a[ix];
          bool desc = ((i & k) == 0);
          if (desc ? (x < y) : (x > y)) { a[i] = y; a[ix] = x; }
        }
      }
      __syncthreads();
    }
  if (t < 1024) top[(size_t)n * 1024 + t] = a[t];
}

// ---- reference IoU>thr test (bit-exact ops/order; a1+a2 commutative) -------
__device__ __forceinline__ bool iou_gt(float4 a, float4 b) {
  float x1 = fmaxf(a.x, b.x), y1 = fmaxf(a.y, b.y);
  float x2 = fminf(a.z, b.z), y2 = fminf(a.w, b.w);
  float inter = fmaxf(x2 - x1, 0.0f) * fmaxf(y2 - y1, 0.0f);
  float a1 = fmaxf(a.z - a.x, 0.0f) * fmaxf(a.w - a.y, 0.0f);
  float a2 = fmaxf(b.z - b.x, 0.0f) * fmaxf(b.w - b.y, 0.0f);
  return inter / fmaxf(a1 + a2 - inter, 1e-9f) > NMSTHR;
}

// ---- K3: fused decode + per-class greedy NMS + ranked output ---------------
// Key fact: ml_nms class offset (c+1)*1281 makes cross-class IoU exactly 0,
// so greedy NMS decomposes into 80 independent per-class chains (~13 boxes).
__global__ __launch_bounds__(1024) void k_nms(const u64* __restrict__ top,
                                              const int* __restrict__ gnc,
                                              const float* __restrict__ reg,
                                              const float* __restrict__ anch,
                                              float4* __restrict__ boxScr,
                                              float* __restrict__ out) {
  __shared__ float4 nbL[1024];                   // offset boxes  (16 KB)
  __shared__ float dL[1024];                     // det scores     (4 KB)
  __shared__ unsigned char clsL[1024];           // class per box  (1 KB)
  __shared__ unsigned short ord[NC * CCAP];      // class lists   (20 KB)
  __shared__ int ccnt[NC];
  __shared__ unsigned short keptIdx[16 * CCAP];  // per-wave kept  (4 KB)
  __shared__ unsigned char keptFlag[1024];
  __shared__ int ss[1024];
  const int n = blockIdx.x, t = threadIdx.x, lane = t & 63, wv = t >> 6;
  // ---- phase 0: decode ----
  const int ncand = gnc[n];
  u64 pk = top[(size_t)n * 1024 + t];
  float4 bx = {0, 0, 0, 0}, nbv = {0, 0, 0, 0};
  float d = 0.0f;
  int c = 0;
  if (t < PREK && t < ncand && pk != 0ULL) {
    float s = __uint_as_float((u32)(pk >> 32));
    u32 idx = ~(u32)pk;
    int loc = idx / NC; c = idx - loc * NC;
    float r0 = reg[((size_t)n * 4 + 0) * HW + loc];
    float r1 = reg[((size_t)n * 4 + 1) * HW + loc];
    float r2 = reg[((size_t)n * 4 + 2) * HW + loc];
    float r3 = reg[((size_t)n * 4 + 3) * HW + loc];
    float a0 = anch[loc * 4 + 0], a1 = anch[loc * 4 + 1];
    float a2 = anch[loc * 4 + 2], a3 = anch[loc * 4 + 3];
    float w = a2 - a0 + 1.0f, h = a3 - a1 + 1.0f;
    float cx = a0 + 0.5f * w, cy = a1 + 0.5f * h;
    float dx = r0 / 10.0f, dy = r1 / 10.0f;
    float dw = fminf(r2 / 5.0f, CLIPDWH), dh = fminf(r3 / 5.0f, CLIPDWH);
    float pcx = dx * w + cx, pcy = dy * h + cy;
    float pw = expf(dw) * w, ph = expf(dh) * h;
    float x1 = pcx - 0.5f * pw, y1 = pcy - 0.5f * ph;
    float x2 = pcx + 0.5f * pw - 1.0f, y2 = pcy + 0.5f * ph - 1.0f;
    x1 = fminf(fmaxf(x1, 0.0f), IMGM1); y1 = fminf(fmaxf(y1, 0.0f), IMGM1);
    x2 = fminf(fmaxf(x2, 0.0f), IMGM1); y2 = fminf(fmaxf(y2, 0.0f), IMGM1);
    float wsz = x2 - x1 + 1.0f, hsz = y2 - y1 + 1.0f;
    if (wsz >= 0.0f && hsz >= 0.0f) d = sqrtf(s);
    bx = {x1, y1, x2, y2};
    float off = (float)(c + 1) * OFFMUL;        // reference adds offset AFTER clip
    nbv = {x1 + off, y1 + off, x2 + off, y2 + off};
  }
  nbL[t] = nbv; dL[t] = d; clsL[t] = (unsigned char)c; keptFlag[t] = 0;
  if (t < PREK) boxScr[n * PREK + t] = bx;       // scratch for output phase
  if (t < NC) ccnt[t] = 0;
  __syncthreads();
  // ---- phase 1: stable per-class lists (thread c scans; broadcast reads) ----
  if (t < NC) {
    int pos = 0;
    for (int k = 0; k < PREK; ++k)
      if (dL[k] > 0.0f && clsL[k] == (unsigned char)t) {
        if (pos < CCAP) ord[t * CCAP + pos] = (unsigned short)k;
        ++pos;
      }
    ccnt[t] = pos < CCAP ? pos : CCAP;
  }
  __syncthreads();
  // ---- phase 2: per-class greedy NMS; wave wv owns classes wv, wv+16, ... ----
  for (int cc = wv; cc < NC; cc += 16) {
    const int ncls = ccnt[cc];
    if (ncls == 0) continue;
    int nkept = 0;
    for (int s0 = 0; s0 < ncls; s0 += 64) {
      const int j = s0 + lane;
      const bool inr = j < ncls;
      const int myk = inr ? ord[cc * CCAP + j] : 0;
      const float4 mb = nbL[myk];
      // dead vs kept boxes of earlier chunks (uniform addr -> LDS broadcast)
      bool dead = false;
      for (int tt = 0; tt < nkept; ++tt)
        dead |= iou_gt(nbL[keptIdx[wv * CCAP + tt]], mb);
      // within-chunk suppressed-by mask (uniform addr -> LDS broadcast)
      const int lim = (ncls - s0) < 64 ? (ncls - s0) : 64;
      u64 supby = 0;
      for (int i = 0; i < lim; ++i) {
        bool sgt = iou_gt(nbL[ord[cc * CCAP + s0 + i]], mb);
        if (i < lane) supby |= (u64)sgt << i;
      }
      // serial resolution, one iteration per KEPT box (uniform values)
      u64 live = __ballot(inr && !dead);
      u64 keptm = 0;
      while (true) {
        u64 rem = live & ~keptm;
        if (!rem) break;
        int i = __ffsll(rem) - 1;
        keptm |= 1ULL << i;
        u64 supped = __ballot((supby >> i) & 1ULL);
        live &= ~(supped & ~((2ULL << i) - 1ULL)); // only later boxes die
      }
      // append kept (in order) to per-wave kept list; mark global flags
      int myrank = nkept + __popcll(keptm & ((1ULL << lane) - 1ULL));
      if ((keptm >> lane) & 1ULL) {
        keptIdx[wv * CCAP + myrank] = (unsigned short)myk;
        keptFlag[myk] = 1;
      }
      nkept += __popcll(keptm);
    }
  }
  __syncthreads();
  // ---- phase 3: rank kept boxes (prefix scan) and emit top-200 ----
  const int flag = keptFlag[t];
  ss[t] = flag;
  __syncthreads();
  for (int off = 1; off < 1024; off <<= 1) {
    int v = (t >= off) ? ss[t - off] : 0;
    __syncthreads();
    ss[t] += v;
    __syncthreads();
  }
  if (flag) {
    int rank = ss[t] - 1;
    if (rank < POSTK) {
      float4 b = boxScr[n * PREK + t];
      float* o = out + ((size_t)n * POSTK + rank) * 5;
      o[0] = b.x; o[1] = b.y; o[2] = b.z; o[3] = b.w; o[4] = dL[t];
    }
  }
}

// ---- launch -----------------------------------------------------------------
extern "C" void kernel_launch(void* const* d_in, const int* in_sizes, int n_in,
                              void* d_out, int out_size, void* d_ws, size_t ws_size,
                              hipStream_t stream) {
  (void)in_sizes; (void)n_in; (void)ws_size;
  const float* cls  = (const float*)d_in[0];
  const float* reg  = (const float*)d_in[1];
  const float* ctr  = (const float*)d_in[2];
  const float* anch = (const float*)d_in[3];
  float* out = (float*)d_out;
  char* ws = (char*)d_ws;

  int*    gcount = (int*)(ws + 0);             // 64
  int*    gnc    = (int*)(ws + 64);            // 64
  u64*    cand   = (u64*)(ws + 128);           // 16*131072*8 = 16,777,216
  u64*    top    = (u64*)(ws + 16777344);      // 16*1024*8 = 131,072
  float4* boxScr = (float4*)(ws + 16908416);   // 16*1000*16 = 256,000 -> end 17,164,416

  hipMemsetAsync(ws, 0, 128, stream);                          // gcount (+gnc)
  hipMemsetAsync(d_out, 0, (size_t)out_size * sizeof(float), stream);

  dim3 gScan(CHW / EPB, NIMG);                 // 125 x 16 blocks
  k_scan   <<<gScan, 256, 0, stream>>>(cls, ctr, gcount, cand);
  k_selsort<<<NIMG, 1024, 0, stream>>>(cand, gcount, top, gnc);
  k_nms    <<<NIMG, 1024, 0, stream>>>(top, gnc, reg, anch, boxScr, out);
}